// Round 10
// baseline (378.452 us; speedup 1.0000x reference)
//
#include <hip/hip_runtime.h>
#include <hip/hip_bf16.h>

#define FEAT 128

typedef unsigned int uint32;
typedef unsigned short ushort16;
typedef __attribute__((ext_vector_type(8))) short short8;
typedef __attribute__((ext_vector_type(4))) float v4f;
typedef __attribute__((ext_vector_type(2))) float f32x2;

// ---- bf16 helpers (RNE round; bf16->f32 is exact shift) ---------------------
__device__ __forceinline__ ushort16 f2bf(float f) {
    uint32 u = __float_as_uint(f);
    u += 0x7fffu + ((u >> 16) & 1u);
    return (ushort16)(u >> 16);
}
__device__ __forceinline__ float bflo(uint32 u) { return __uint_as_float(u << 16); }
__device__ __forceinline__ float bfhi(uint32 u) { return __uint_as_float(u & 0xffff0000u); }
__device__ __forceinline__ f32x2 up2(uint32 u) { return (f32x2){bflo(u), bfhi(u)}; }

// ---------------- shared gemm body: half-W-per-wave register-resident --------
__device__ __forceinline__ void gemm_body(const float* __restrict__ A,
                                          const ushort16* __restrict__ Wt,
                                          ushort16* __restrict__ Ch, int n,
                                          int pairId, int pairStride,
                                          int tile0, int tile1, int t) {
    const int w = t >> 6;
    const int lane = t & 63;
    const int quad = lane >> 4;
    const int l16 = lane & 15;
    const int colBase = (w & 1) * 64;

    short8 wf[4][4];
#pragma unroll
    for (int ct = 0; ct < 4; ct++) {
        const ushort16* wp = Wt + (size_t)(colBase + ct * 16 + l16) * FEAT + quad * 8;
#pragma unroll
        for (int ks = 0; ks < 4; ks++) wf[ct][ks] = *(const short8*)(wp + ks * 32);
    }

    int tile = tile0 + pairId;
    if (tile >= tile1) return;

    auto loadA = [&](int tl, short8 (&a)[4]) {
        const int rowi = tl * 16 + l16;
        if (rowi < n) {
#pragma unroll
            for (int ks = 0; ks < 4; ks++) {
                const float* ap = A + (size_t)rowi * FEAT + quad * 8 + ks * 32;
                float4 f0 = *(const float4*)ap;
                float4 f1 = *(const float4*)(ap + 4);
                short8 v;
                v[0] = f2bf(f0.x); v[1] = f2bf(f0.y); v[2] = f2bf(f0.z); v[3] = f2bf(f0.w);
                v[4] = f2bf(f1.x); v[5] = f2bf(f1.y); v[6] = f2bf(f1.z); v[7] = f2bf(f1.w);
                a[ks] = v;
            }
        } else {
#pragma unroll
            for (int ks = 0; ks < 4; ks++) a[ks] = (short8)0;
        }
    };

    short8 aCur[4];
    loadA(tile, aCur);

    while (tile < tile1) {
        const int nextTile = tile + pairStride;
        short8 aNxt[4];
        if (nextTile < tile1) loadA(nextTile, aNxt);

        v4f acc[4];
#pragma unroll
        for (int ct = 0; ct < 4; ct++) acc[ct] = (v4f)0.f;
#pragma unroll
        for (int ct = 0; ct < 4; ct++)
#pragma unroll
            for (int ks = 0; ks < 4; ks++)
                acc[ct] = __builtin_amdgcn_mfma_f32_16x16x32_bf16(wf[ct][ks], aCur[ks], acc[ct], 0, 0, 0);

        const int rowi = tile * 16 + l16;
        if (rowi < n) {
#pragma unroll
            for (int ct = 0; ct < 4; ct++) {
                uint2 o;
                o.x = (uint32)f2bf(acc[ct][0]) | ((uint32)f2bf(acc[ct][1]) << 16);
                o.y = (uint32)f2bf(acc[ct][2]) | ((uint32)f2bf(acc[ct][3]) << 16);
                *(uint2*)(Ch + (size_t)rowi * FEAT + colBase + ct * 16 + quad * 4) = o;
            }
        }

        tile = nextTile;
#pragma unroll
        for (int ks = 0; ks < 4; ks++) aCur[ks] = aNxt[ks];
    }
}

// ---------------- pre: zero counts + W01=W0@W1 + zero(P) + zero(flagval) -----
__global__ __launch_bounds__(256) void pre_kernel(int* __restrict__ counts, int n,
                                                  const float* __restrict__ W0,
                                                  const float* __restrict__ W1,
                                                  ushort16* __restrict__ W01t,
                                                  float* __restrict__ Pbuf,
                                                  int* __restrict__ flagval) {
    int b = blockIdx.x;
    int t = threadIdx.x;
    if (b < 100) {
        int idx = (b * 256 + t) * 4;
        if (idx + 3 < n) {
            *(int4*)(counts + idx) = make_int4(0, 0, 0, 0);
        } else {
            for (int i = idx; i < n; i++) counts[i] = 0;
        }
    } else if (b < 164) {
        __shared__ float sW0[2][FEAT];
        int wb = b - 100;  // [0, 64)
        int lk = t >> 7;
        int ncol = t & 127;
        int k = wb * 2 + lk;
        sW0[lk][ncol] = W0[(size_t)k * FEAT + ncol];
        __syncthreads();
        float acc = 0.f;
#pragma unroll 4
        for (int j = 0; j < FEAT; j++)
            acc += sW0[lk][j] * W1[(size_t)j * FEAT + ncol];
        W01t[(size_t)ncol * FEAT + k] = f2bf(acc);  // [n][k], transposed for MFMA
    } else if (b < 196) {
        int zb = b - 164;  // [0, 32): 512*128 floats
        float4 z = make_float4(0.f, 0.f, 0.f, 0.f);
        float* p = Pbuf + (size_t)zb * 2048 + t * 8;
        *(float4*)p = z;
        *(float4*)(p + 4) = z;
    } else {
        if (t < 128) flagval[t] = 0;  // scan lookback flags
    }
}

// ---------------- FUSED hist + gemm-half-A -----------------------------------
__global__ __launch_bounds__(256) void histgemmA_kernel(const int* __restrict__ col,
                                                        int* __restrict__ counts, int E,
                                                        const float* __restrict__ A,
                                                        const ushort16* __restrict__ Wt,
                                                        ushort16* __restrict__ Ch, int n) {
    const int b = blockIdx.x;
    const int r9 = b % 9;
    const int g9 = b / 9;
    const int t = threadIdx.x;
    if (r9 >= 4) {
        // hist role: 5/9 -> hist block id in [0, 640)
        int hb = g9 * 5 + (r9 - 4);
        int id = hb * 256 + t;
        if (id * 4 + 3 < E) {
            int4 c4 = *(const int4*)(col + id * 4);
            atomicAdd(&counts[c4.x], 1);
            atomicAdd(&counts[c4.y], 1);
            atomicAdd(&counts[c4.z], 1);
            atomicAdd(&counts[c4.w], 1);
        } else {
            for (int e = id * 4; e < E; e++) atomicAdd(&counts[col[e]], 1);
        }
        return;
    }
    // gemm role: 4/9 -> gemm block id in [0, 512); 1024 wave-pairs, stride 1024
    int gb = g9 * 4 + r9;
    gemm_body(A, Wt, Ch, n, gb * 2 + ((t >> 6) >> 1), 1024, 0, 3125, t);
}

// ---------------- merged CSR scan (publish + PARALLEL lookback, R7-proven) ---
__global__ __launch_bounds__(256) void scan_chain(const int* __restrict__ counts,
                                                  int* __restrict__ flagval,
                                                  int* __restrict__ off, int* __restrict__ nxt,
                                                  float* __restrict__ dinv, int n) {
    __shared__ int s[256];
    __shared__ int sb[256];
    const int b = blockIdx.x;
    const int base = b * 1024;
    const int t = threadIdx.x;
    int c[4];
    int sum = 0;
#pragma unroll
    for (int i = 0; i < 4; i++) {
        int idx = base + t * 4 + i;
        c[i] = (idx < n) ? counts[idx] : 0;
        sum += c[i];
    }
    int v0 = sum;
    s[t] = sum;
    __syncthreads();
    for (int o = 1; o < 256; o <<= 1) {
        int v = (t >= o) ? s[t - o] : 0;
        __syncthreads();
        s[t] += v;
        __syncthreads();
    }
    if (t == 255) atomicExch(&flagval[b], s[255] + 1);  // publish (no wait)
    // parallel lookback: thread t polls predecessor t's flag
    int lv = 0;
    if (t < b) {
        for (;;) {
            lv = atomicAdd(&flagval[t], 0);
            if (lv != 0) break;
            __builtin_amdgcn_s_sleep(2);
        }
        lv -= 1;
    }
    sb[t] = lv;
    __syncthreads();
    for (int o = 128; o > 0; o >>= 1) {
        if (t < o) sb[t] += sb[t + o];
        __syncthreads();
    }
    const int sBase = sb[0];
    int excl = s[t] - v0 + sBase;
#pragma unroll
    for (int i = 0; i < 4; i++) {
        int idx = base + t * 4 + i;
        if (idx < n) {
            off[idx] = excl;
            nxt[idx] = excl;
            dinv[idx] = rsqrtf((float)(c[i] + 1));  // +1 = self loop
        }
        excl += c[i];
    }
    if (b == gridDim.x - 1 && t == 255) off[n] = excl;  // == E
}

// ---------------- FUSED fill + gemm-half-B -----------------------------------
__global__ __launch_bounds__(256) void fillgemmB_kernel(const float* __restrict__ A,
                                                        const ushort16* __restrict__ Wt,
                                                        ushort16* __restrict__ Ch, int n,
                                                        const int* __restrict__ row,
                                                        const int* __restrict__ col,
                                                        int* __restrict__ nxt,
                                                        int* __restrict__ srcArr, int E) {
    const int b = blockIdx.x;
    const int r7 = b % 7;
    const int g7 = b / 7;
    const int t = threadIdx.x;
    if (r7 >= 2) {
        // fill role: 5/7 -> fill block id in [0, 2560)
        int fb = g7 * 5 + (r7 - 2);
        int e = fb * 256 + t;
        if (e < E) {
            int c = col[e], r = row[e];
            int p = atomicAdd(&nxt[c], 1);
            __builtin_nontemporal_store(r, &srcArr[p]);
        }
        return;
    }
    // gemm role: 2/7 -> gemm block id in [0, 1024); 2048 wave-pairs, stride 2048
    int gb = g7 * 2 + r7;
    gemm_body(A, Wt, Ch, n, gb * 2 + ((t >> 6) >> 1), 2048, 3125, 6250, t);
}

// ---------------- gather-propagate, ONE NODE PER 16-LANE GROUP (R9-proven) ---
// Each group owns ONE node, walks ALL its edges unroll-4: 16 independent
// row-loads in flight per wave, no shfl, all lanes store.  R9: 48 -> ~39us.
//   MODE 0: raw input.  writes dc^2 * (dc*T[c] + sum dinv[src]*T[src]).
//   MODE 1: prescaled.  writes dc^2 * leaky(T[c] + sum T[src]).
template <int MODE>
__global__ __launch_bounds__(256) void gather_kernel(const int* __restrict__ off,
                                                     const int* __restrict__ srcArr,
                                                     const float* __restrict__ dinv,
                                                     const uint4* __restrict__ table,
                                                     ushort16* __restrict__ Hh, int n) {
    const int t = threadIdx.x;
    const int lane = t & 63;
    const int grp = lane >> 4;
    const int l16 = lane & 15;
    const int node = blockIdx.x * 16 + (t >> 6) * 4 + grp;  // one node per group
    if (node >= n) return;

    const float dc = dinv[node];

    // self-loop term
    uint4 v = table[(size_t)node * 16 + l16];
    f32x2 acc[4];
    if (MODE == 0) {
        f32x2 w0 = (f32x2){dc, dc};
        acc[0] = w0 * up2(v.x);
        acc[1] = w0 * up2(v.y);
        acc[2] = w0 * up2(v.z);
        acc[3] = w0 * up2(v.w);
    } else {
        acc[0] = up2(v.x);
        acc[1] = up2(v.y);
        acc[2] = up2(v.z);
        acc[3] = up2(v.w);
    }

    const int s = off[node], e = off[node + 1];
    int i = s;
    for (; i + 3 < e; i += 4) {
        int r0 = srcArr[i];
        int r1 = srcArr[i + 1];
        int r2 = srcArr[i + 2];
        int r3 = srcArr[i + 3];
        uint4 u0 = table[(size_t)r0 * 16 + l16];
        uint4 u1 = table[(size_t)r1 * 16 + l16];
        uint4 u2 = table[(size_t)r2 * 16 + l16];
        uint4 u3 = table[(size_t)r3 * 16 + l16];
        if (MODE == 0) {
            f32x2 n0 = (f32x2){dinv[r0], dinv[r0]};
            f32x2 n1 = (f32x2){dinv[r1], dinv[r1]};
            f32x2 n2 = (f32x2){dinv[r2], dinv[r2]};
            f32x2 n3 = (f32x2){dinv[r3], dinv[r3]};
            acc[0] += n0 * up2(u0.x) + n1 * up2(u1.x);
            acc[1] += n0 * up2(u0.y) + n1 * up2(u1.y);
            acc[2] += n0 * up2(u0.z) + n1 * up2(u1.z);
            acc[3] += n0 * up2(u0.w) + n1 * up2(u1.w);
            acc[0] += n2 * up2(u2.x) + n3 * up2(u3.x);
            acc[1] += n2 * up2(u2.y) + n3 * up2(u3.y);
            acc[2] += n2 * up2(u2.z) + n3 * up2(u3.z);
            acc[3] += n2 * up2(u2.w) + n3 * up2(u3.w);
        } else {
            acc[0] += up2(u0.x) + up2(u1.x) + up2(u2.x) + up2(u3.x);
            acc[1] += up2(u0.y) + up2(u1.y) + up2(u2.y) + up2(u3.y);
            acc[2] += up2(u0.z) + up2(u1.z) + up2(u2.z) + up2(u3.z);
            acc[3] += up2(u0.w) + up2(u1.w) + up2(u2.w) + up2(u3.w);
        }
    }
    for (; i < e; i++) {
        int r0 = srcArr[i];
        uint4 u0 = table[(size_t)r0 * 16 + l16];
        if (MODE == 0) {
            f32x2 n0 = (f32x2){dinv[r0], dinv[r0]};
            acc[0] += n0 * up2(u0.x);
            acc[1] += n0 * up2(u0.y);
            acc[2] += n0 * up2(u0.z);
            acc[3] += n0 * up2(u0.w);
        } else {
            acc[0] += up2(u0.x);
            acc[1] += up2(u0.y);
            acc[2] += up2(u0.z);
            acc[3] += up2(u0.w);
        }
    }

    float b[8] = {acc[0].x, acc[0].y, acc[1].x, acc[1].y,
                  acc[2].x, acc[2].y, acc[3].x, acc[3].y};
    const float sc = dc * dc;
    if (MODE == 1) {
#pragma unroll
        for (int j = 0; j < 8; j++) {
            float h = b[j];
            h = (h >= 0.f) ? h : 0.01f * h;
            b[j] = sc * h;
        }
    } else {
#pragma unroll
        for (int j = 0; j < 8; j++) b[j] *= sc;
    }
    uint4 o;
    o.x = (uint32)f2bf(b[0]) | ((uint32)f2bf(b[1]) << 16);
    o.y = (uint32)f2bf(b[2]) | ((uint32)f2bf(b[3]) << 16);
    o.z = (uint32)f2bf(b[4]) | ((uint32)f2bf(b[5]) << 16);
    o.w = (uint32)f2bf(b[6]) | ((uint32)f2bf(b[7]) << 16);
    *(uint4*)(Hh + (size_t)node * FEAT + l16 * 8) = o;
}

// ---------------- gather pass 3 + pool, ONE GROUP = 8 SERIAL NODES (R10) -----
// R9 structure ported to the pool pass: each 16-lane group owns 8 consecutive
// nodes (serial).  The group's lanes cover the full 256B row (16 x 16B), so
// after walking all edges each lane's acc[8] IS the finished 8-feature slice
// — no shfl.  Pool accumulator pacc[8] stays in registers (R3 mechanism);
// flush on graph transition = 8 scalar atomics/lane (~13K flushes, ~1.7M
// atomic ops — R2-proven harmless rate).  MLP: 8 -> 16 row-loads in flight
// per wave; 256 shfl+adds per wave eliminated.
__global__ __launch_bounds__(256) void gatherpool_kernel(const int* __restrict__ off,
                                                         const int* __restrict__ srcArr,
                                                         const float* __restrict__ dinv,
                                                         const uint4* __restrict__ table,
                                                         const int* __restrict__ batch,
                                                         float* __restrict__ P, int n) {
    const int t = threadIdx.x;
    const int lane = t & 63;
    const int grp = lane >> 4;
    const int l16 = lane & 15;
    const int group = blockIdx.x * 16 + (t >> 6) * 4 + grp;  // global group id

    const int node0 = group * 8;
    if (node0 >= n) return;
    const int node1 = min(node0 + 8, n);

    float pacc[8];
#pragma unroll
    for (int j = 0; j < 8; j++) pacc[j] = 0.f;
    int cur = batch[node0];

    for (int node = node0; node < node1; node++) {
        const float dc = dinv[node];

        // self-loop term (prescaled input: raw add)
        uint4 v = table[(size_t)node * 16 + l16];
        f32x2 acc[4];
        acc[0] = up2(v.x);
        acc[1] = up2(v.y);
        acc[2] = up2(v.z);
        acc[3] = up2(v.w);

        const int s = off[node], e = off[node + 1];
        int i = s;
        for (; i + 3 < e; i += 4) {
            int r0 = srcArr[i];
            int r1 = srcArr[i + 1];
            int r2 = srcArr[i + 2];
            int r3 = srcArr[i + 3];
            uint4 u0 = table[(size_t)r0 * 16 + l16];
            uint4 u1 = table[(size_t)r1 * 16 + l16];
            uint4 u2 = table[(size_t)r2 * 16 + l16];
            uint4 u3 = table[(size_t)r3 * 16 + l16];
            acc[0] += up2(u0.x) + up2(u1.x) + up2(u2.x) + up2(u3.x);
            acc[1] += up2(u0.y) + up2(u1.y) + up2(u2.y) + up2(u3.y);
            acc[2] += up2(u0.z) + up2(u1.z) + up2(u2.z) + up2(u3.z);
            acc[3] += up2(u0.w) + up2(u1.w) + up2(u2.w) + up2(u3.w);
        }
        for (; i < e; i++) {
            int r0 = srcArr[i];
            uint4 u0 = table[(size_t)r0 * 16 + l16];
            acc[0] += up2(u0.x);
            acc[1] += up2(u0.y);
            acc[2] += up2(u0.z);
            acc[3] += up2(u0.w);
        }

        int g = batch[node];  // uniform within the group
        if (g != cur) {       // group-uniform branch (sorted batch)
            float* Pr = P + (size_t)cur * FEAT + l16 * 8;
#pragma unroll
            for (int j = 0; j < 8; j++) atomicAdd(Pr + j, pacc[j]);
#pragma unroll
            for (int j = 0; j < 8; j++) pacc[j] = 0.f;
            cur = g;
        }
        pacc[0] += dc * acc[0].x;
        pacc[1] += dc * acc[0].y;
        pacc[2] += dc * acc[1].x;
        pacc[3] += dc * acc[1].y;
        pacc[4] += dc * acc[2].x;
        pacc[5] += dc * acc[2].y;
        pacc[6] += dc * acc[3].x;
        pacc[7] += dc * acc[3].y;
    }
    // final flush
    float* Pr = P + (size_t)cur * FEAT + l16 * 8;
#pragma unroll
    for (int j = 0; j < 8; j++) atomicAdd(Pr + j, pacc[j]);
}

// ---------------- final tiny GEMM: out[g] = P[g] @ W2 (fp32) -----------------
__global__ __launch_bounds__(128) void pgemm_kernel(const float* __restrict__ P,
                                                    const float* __restrict__ W2,
                                                    float* __restrict__ out) {
    __shared__ float sP[FEAT];
    const int g = blockIdx.x;
    const int t = threadIdx.x;
    sP[t] = P[(size_t)g * FEAT + t];
    __syncthreads();
    float o = 0.f;
#pragma unroll 4
    for (int k = 0; k < FEAT; k++) o += sP[k] * W2[(size_t)k * FEAT + t];
    out[(size_t)g * FEAT + t] = o;
}

extern "C" void kernel_launch(void* const* d_in, const int* in_sizes, int n_in,
                              void* d_out, int out_size, void* d_ws, size_t ws_size,
                              hipStream_t stream) {
    const float* x = (const float*)d_in[0];
    const int* ei = (const int*)d_in[1];
    const int* batch = (const int*)d_in[2];
    const float* W0 = (const float*)d_in[3];
    const float* W1 = (const float*)d_in[4];
    const float* W2 = (const float*)d_in[5];
    float* out = (float*)d_out;

    const int N = in_sizes[0] / FEAT;  // 100000
    const int E = in_sizes[1] / 2;     // 640000
    const int G = out_size / FEAT;     // 512

    const int* rowI = ei;
    const int* colI = ei + E;

    char* ws = (char*)d_ws;
    auto take = [&](size_t bytes) {
        char* p = ws;
        ws += (bytes + 15) & ~(size_t)15;
        return p;
    };
    int* counts    = (int*)take((size_t)N * 4);
    int* off       = (int*)take((size_t)(N + 1) * 4);
    int* nxt       = (int*)take((size_t)N * 4);
    float* dinv    = (float*)take((size_t)N * 4);
    int* flagval   = (int*)take(128 * 4);
    int* srcArr    = (int*)take((size_t)E * 4);
    ushort16* W01t = (ushort16*)take((size_t)16384 * 2);
    float* Pbuf    = (float*)take((size_t)G * FEAT * 4);
    ushort16* bufA = (ushort16*)take((size_t)N * FEAT * 2);
    ushort16* bufB = (ushort16*)take((size_t)N * FEAT * 2);

    const int nb = (N + 1023) / 1024;  // 98

    // ---- pre: zero counts + W01 + zero P + zero flags (one dispatch) ----
    pre_kernel<<<197, 256, 0, stream>>>(counts, N, W0, W1, W01t, Pbuf, flagval);

    // ---- hist (latency) || gemm-half-A (tiles [0,3125)) ----
    histgemmA_kernel<<<128 * 9, 256, 0, stream>>>(colI, counts, E, x, W01t, bufA, N);

    // ---- CSR scan (merged, parallel lookback, one dispatch) ----
    scan_chain<<<nb, 256, 0, stream>>>(counts, flagval, off, nxt, dinv, N);

    // ---- fill (latency) || gemm-half-B (tiles [3125,6250)) ----
    fillgemmB_kernel<<<512 * 7, 256, 0, stream>>>(x, W01t, bufA, N,
                                                  rowI, colI, nxt, srcArr, E);

    const int gatBlocks = (N + 15) / 16;  // 6250: 16 nodes/block, 1 node/group
    // ---- pass 1: bufB = dinv * (A Y)   (raw input, prescaled output) ----
    gather_kernel<0><<<gatBlocks, 256, 0, stream>>>(off, srcArr, dinv,
                                                    (const uint4*)bufA, bufB, N);
    // ---- pass 2: bufA = dinv * leaky(A H1)   (prescaled in & out) ----
    gather_kernel<1><<<gatBlocks, 256, 0, stream>>>(off, srcArr, dinv,
                                                    (const uint4*)bufB, bufA, N);
    // ---- pass 3: P += pool(A H3)  (one group = 8 serial nodes, reg pool) ----
    const int nGroups = (N + 7) / 8;                 // 12500 groups
    const int poolBlocks = (nGroups + 15) / 16;      // 782 blocks x 16 groups
    gatherpool_kernel<<<poolBlocks, 256, 0, stream>>>(off, srcArr, dinv,
                                                      (const uint4*)bufA, batch,
                                                      Pbuf, N);
    // ---- out = P @ W2 ----
    pgemm_kernel<<<G, 128, 0, stream>>>(Pbuf, W2, out);
}

// Round 11
// 316.887 us; speedup vs baseline: 1.1943x; 1.1943x over previous
//
#include <hip/hip_runtime.h>
#include <hip/hip_bf16.h>

#define FEAT 128

typedef unsigned int uint32;
typedef unsigned short ushort16;
typedef __attribute__((ext_vector_type(8))) short short8;
typedef __attribute__((ext_vector_type(4))) float v4f;
typedef __attribute__((ext_vector_type(2))) float f32x2;

// ---- bf16 helpers (RNE round; bf16->f32 is exact shift) ---------------------
__device__ __forceinline__ ushort16 f2bf(float f) {
    uint32 u = __float_as_uint(f);
    u += 0x7fffu + ((u >> 16) & 1u);
    return (ushort16)(u >> 16);
}
__device__ __forceinline__ float bflo(uint32 u) { return __uint_as_float(u << 16); }
__device__ __forceinline__ float bfhi(uint32 u) { return __uint_as_float(u & 0xffff0000u); }
__device__ __forceinline__ f32x2 up2(uint32 u) { return (f32x2){bflo(u), bfhi(u)}; }

// ---------------- shared gemm body: half-W-per-wave register-resident --------
__device__ __forceinline__ void gemm_body(const float* __restrict__ A,
                                          const ushort16* __restrict__ Wt,
                                          ushort16* __restrict__ Ch, int n,
                                          int pairId, int pairStride,
                                          int tile0, int tile1, int t) {
    const int w = t >> 6;
    const int lane = t & 63;
    const int quad = lane >> 4;
    const int l16 = lane & 15;
    const int colBase = (w & 1) * 64;

    short8 wf[4][4];
#pragma unroll
    for (int ct = 0; ct < 4; ct++) {
        const ushort16* wp = Wt + (size_t)(colBase + ct * 16 + l16) * FEAT + quad * 8;
#pragma unroll
        for (int ks = 0; ks < 4; ks++) wf[ct][ks] = *(const short8*)(wp + ks * 32);
    }

    int tile = tile0 + pairId;
    if (tile >= tile1) return;

    auto loadA = [&](int tl, short8 (&a)[4]) {
        const int rowi = tl * 16 + l16;
        if (rowi < n) {
#pragma unroll
            for (int ks = 0; ks < 4; ks++) {
                const float* ap = A + (size_t)rowi * FEAT + quad * 8 + ks * 32;
                float4 f0 = *(const float4*)ap;
                float4 f1 = *(const float4*)(ap + 4);
                short8 v;
                v[0] = f2bf(f0.x); v[1] = f2bf(f0.y); v[2] = f2bf(f0.z); v[3] = f2bf(f0.w);
                v[4] = f2bf(f1.x); v[5] = f2bf(f1.y); v[6] = f2bf(f1.z); v[7] = f2bf(f1.w);
                a[ks] = v;
            }
        } else {
#pragma unroll
            for (int ks = 0; ks < 4; ks++) a[ks] = (short8)0;
        }
    };

    short8 aCur[4];
    loadA(tile, aCur);

    while (tile < tile1) {
        const int nextTile = tile + pairStride;
        short8 aNxt[4];
        if (nextTile < tile1) loadA(nextTile, aNxt);

        v4f acc[4];
#pragma unroll
        for (int ct = 0; ct < 4; ct++) acc[ct] = (v4f)0.f;
#pragma unroll
        for (int ct = 0; ct < 4; ct++)
#pragma unroll
            for (int ks = 0; ks < 4; ks++)
                acc[ct] = __builtin_amdgcn_mfma_f32_16x16x32_bf16(wf[ct][ks], aCur[ks], acc[ct], 0, 0, 0);

        const int rowi = tile * 16 + l16;
        if (rowi < n) {
#pragma unroll
            for (int ct = 0; ct < 4; ct++) {
                uint2 o;
                o.x = (uint32)f2bf(acc[ct][0]) | ((uint32)f2bf(acc[ct][1]) << 16);
                o.y = (uint32)f2bf(acc[ct][2]) | ((uint32)f2bf(acc[ct][3]) << 16);
                *(uint2*)(Ch + (size_t)rowi * FEAT + colBase + ct * 16 + quad * 4) = o;
            }
        }

        tile = nextTile;
#pragma unroll
        for (int ks = 0; ks < 4; ks++) aCur[ks] = aNxt[ks];
    }
}

// ---------------- pre: zero counts + W01=W0@W1 + zero(P) + zero(flagval) -----
__global__ __launch_bounds__(256) void pre_kernel(int* __restrict__ counts, int n,
                                                  const float* __restrict__ W0,
                                                  const float* __restrict__ W1,
                                                  ushort16* __restrict__ W01t,
                                                  float* __restrict__ Pbuf,
                                                  int* __restrict__ flagval) {
    int b = blockIdx.x;
    int t = threadIdx.x;
    if (b < 100) {
        int idx = (b * 256 + t) * 4;
        if (idx + 3 < n) {
            *(int4*)(counts + idx) = make_int4(0, 0, 0, 0);
        } else {
            for (int i = idx; i < n; i++) counts[i] = 0;
        }
    } else if (b < 164) {
        __shared__ float sW0[2][FEAT];
        int wb = b - 100;  // [0, 64)
        int lk = t >> 7;
        int ncol = t & 127;
        int k = wb * 2 + lk;
        sW0[lk][ncol] = W0[(size_t)k * FEAT + ncol];
        __syncthreads();
        float acc = 0.f;
#pragma unroll 4
        for (int j = 0; j < FEAT; j++)
            acc += sW0[lk][j] * W1[(size_t)j * FEAT + ncol];
        W01t[(size_t)ncol * FEAT + k] = f2bf(acc);  // [n][k], transposed for MFMA
    } else if (b < 196) {
        int zb = b - 164;  // [0, 32): 512*128 floats
        float4 z = make_float4(0.f, 0.f, 0.f, 0.f);
        float* p = Pbuf + (size_t)zb * 2048 + t * 8;
        *(float4*)p = z;
        *(float4*)(p + 4) = z;
    } else {
        if (t < 128) flagval[t] = 0;  // scan lookback flags
    }
}

// ---------------- FUSED hist + gemm-half-A -----------------------------------
__global__ __launch_bounds__(256) void histgemmA_kernel(const int* __restrict__ col,
                                                        int* __restrict__ counts, int E,
                                                        const float* __restrict__ A,
                                                        const ushort16* __restrict__ Wt,
                                                        ushort16* __restrict__ Ch, int n) {
    const int b = blockIdx.x;
    const int r9 = b % 9;
    const int g9 = b / 9;
    const int t = threadIdx.x;
    if (r9 >= 4) {
        // hist role: 5/9 -> hist block id in [0, 640)
        int hb = g9 * 5 + (r9 - 4);
        int id = hb * 256 + t;
        if (id * 4 + 3 < E) {
            int4 c4 = *(const int4*)(col + id * 4);
            atomicAdd(&counts[c4.x], 1);
            atomicAdd(&counts[c4.y], 1);
            atomicAdd(&counts[c4.z], 1);
            atomicAdd(&counts[c4.w], 1);
        } else {
            for (int e = id * 4; e < E; e++) atomicAdd(&counts[col[e]], 1);
        }
        return;
    }
    // gemm role: 4/9 -> gemm block id in [0, 512); 1024 wave-pairs, stride 1024
    int gb = g9 * 4 + r9;
    gemm_body(A, Wt, Ch, n, gb * 2 + ((t >> 6) >> 1), 1024, 0, 3125, t);
}

// ---------------- merged CSR scan (publish + PARALLEL lookback, R7-proven) ---
__global__ __launch_bounds__(256) void scan_chain(const int* __restrict__ counts,
                                                  int* __restrict__ flagval,
                                                  int* __restrict__ off, int* __restrict__ nxt,
                                                  float* __restrict__ dinv, int n) {
    __shared__ int s[256];
    __shared__ int sb[256];
    const int b = blockIdx.x;
    const int base = b * 1024;
    const int t = threadIdx.x;
    int c[4];
    int sum = 0;
#pragma unroll
    for (int i = 0; i < 4; i++) {
        int idx = base + t * 4 + i;
        c[i] = (idx < n) ? counts[idx] : 0;
        sum += c[i];
    }
    int v0 = sum;
    s[t] = sum;
    __syncthreads();
    for (int o = 1; o < 256; o <<= 1) {
        int v = (t >= o) ? s[t - o] : 0;
        __syncthreads();
        s[t] += v;
        __syncthreads();
    }
    if (t == 255) atomicExch(&flagval[b], s[255] + 1);  // publish (no wait)
    // parallel lookback: thread t polls predecessor t's flag
    int lv = 0;
    if (t < b) {
        for (;;) {
            lv = atomicAdd(&flagval[t], 0);
            if (lv != 0) break;
            __builtin_amdgcn_s_sleep(2);
        }
        lv -= 1;
    }
    sb[t] = lv;
    __syncthreads();
    for (int o = 128; o > 0; o >>= 1) {
        if (t < o) sb[t] += sb[t + o];
        __syncthreads();
    }
    const int sBase = sb[0];
    int excl = s[t] - v0 + sBase;
#pragma unroll
    for (int i = 0; i < 4; i++) {
        int idx = base + t * 4 + i;
        if (idx < n) {
            off[idx] = excl;
            nxt[idx] = excl;
            dinv[idx] = rsqrtf((float)(c[i] + 1));  // +1 = self loop
        }
        excl += c[i];
    }
    if (b == gridDim.x - 1 && t == 255) off[n] = excl;  // == E
}

// ---------------- FUSED fill + gemm-half-B -----------------------------------
__global__ __launch_bounds__(256) void fillgemmB_kernel(const float* __restrict__ A,
                                                        const ushort16* __restrict__ Wt,
                                                        ushort16* __restrict__ Ch, int n,
                                                        const int* __restrict__ row,
                                                        const int* __restrict__ col,
                                                        int* __restrict__ nxt,
                                                        int* __restrict__ srcArr, int E) {
    const int b = blockIdx.x;
    const int r7 = b % 7;
    const int g7 = b / 7;
    const int t = threadIdx.x;
    if (r7 >= 2) {
        // fill role: 5/7 -> fill block id in [0, 2560)
        int fb = g7 * 5 + (r7 - 2);
        int e = fb * 256 + t;
        if (e < E) {
            int c = col[e], r = row[e];
            int p = atomicAdd(&nxt[c], 1);
            __builtin_nontemporal_store(r, &srcArr[p]);
        }
        return;
    }
    // gemm role: 2/7 -> gemm block id in [0, 1024); 2048 wave-pairs, stride 2048
    int gb = g7 * 2 + r7;
    gemm_body(A, Wt, Ch, n, gb * 2 + ((t >> 6) >> 1), 2048, 3125, 6250, t);
}

// ---------------- gather-propagate, ONE NODE PER 16-LANE GROUP (R9-proven) ---
// Each group owns ONE node, walks ALL its edges unroll-4: 16 independent
// row-loads in flight per wave, no shfl, all lanes store.  R9: 48 -> ~39us.
//   MODE 0: raw input.  writes dc^2 * (dc*T[c] + sum dinv[src]*T[src]).
//   MODE 1: prescaled.  writes dc^2 * leaky(T[c] + sum T[src]).
template <int MODE>
__global__ __launch_bounds__(256) void gather_kernel(const int* __restrict__ off,
                                                     const int* __restrict__ srcArr,
                                                     const float* __restrict__ dinv,
                                                     const uint4* __restrict__ table,
                                                     ushort16* __restrict__ Hh, int n) {
    const int t = threadIdx.x;
    const int lane = t & 63;
    const int grp = lane >> 4;
    const int l16 = lane & 15;
    const int node = blockIdx.x * 16 + (t >> 6) * 4 + grp;  // one node per group
    if (node >= n) return;

    const float dc = dinv[node];

    // self-loop term
    uint4 v = table[(size_t)node * 16 + l16];
    f32x2 acc[4];
    if (MODE == 0) {
        f32x2 w0 = (f32x2){dc, dc};
        acc[0] = w0 * up2(v.x);
        acc[1] = w0 * up2(v.y);
        acc[2] = w0 * up2(v.z);
        acc[3] = w0 * up2(v.w);
    } else {
        acc[0] = up2(v.x);
        acc[1] = up2(v.y);
        acc[2] = up2(v.z);
        acc[3] = up2(v.w);
    }

    const int s = off[node], e = off[node + 1];
    int i = s;
    for (; i + 3 < e; i += 4) {
        int r0 = srcArr[i];
        int r1 = srcArr[i + 1];
        int r2 = srcArr[i + 2];
        int r3 = srcArr[i + 3];
        uint4 u0 = table[(size_t)r0 * 16 + l16];
        uint4 u1 = table[(size_t)r1 * 16 + l16];
        uint4 u2 = table[(size_t)r2 * 16 + l16];
        uint4 u3 = table[(size_t)r3 * 16 + l16];
        if (MODE == 0) {
            f32x2 n0 = (f32x2){dinv[r0], dinv[r0]};
            f32x2 n1 = (f32x2){dinv[r1], dinv[r1]};
            f32x2 n2 = (f32x2){dinv[r2], dinv[r2]};
            f32x2 n3 = (f32x2){dinv[r3], dinv[r3]};
            acc[0] += n0 * up2(u0.x) + n1 * up2(u1.x);
            acc[1] += n0 * up2(u0.y) + n1 * up2(u1.y);
            acc[2] += n0 * up2(u0.z) + n1 * up2(u1.z);
            acc[3] += n0 * up2(u0.w) + n1 * up2(u1.w);
            acc[0] += n2 * up2(u2.x) + n3 * up2(u3.x);
            acc[1] += n2 * up2(u2.y) + n3 * up2(u3.y);
            acc[2] += n2 * up2(u2.z) + n3 * up2(u3.z);
            acc[3] += n2 * up2(u2.w) + n3 * up2(u3.w);
        } else {
            acc[0] += up2(u0.x) + up2(u1.x) + up2(u2.x) + up2(u3.x);
            acc[1] += up2(u0.y) + up2(u1.y) + up2(u2.y) + up2(u3.y);
            acc[2] += up2(u0.z) + up2(u1.z) + up2(u2.z) + up2(u3.z);
            acc[3] += up2(u0.w) + up2(u1.w) + up2(u2.w) + up2(u3.w);
        }
    }
    for (; i < e; i++) {
        int r0 = srcArr[i];
        uint4 u0 = table[(size_t)r0 * 16 + l16];
        if (MODE == 0) {
            f32x2 n0 = (f32x2){dinv[r0], dinv[r0]};
            acc[0] += n0 * up2(u0.x);
            acc[1] += n0 * up2(u0.y);
            acc[2] += n0 * up2(u0.z);
            acc[3] += n0 * up2(u0.w);
        } else {
            acc[0] += up2(u0.x);
            acc[1] += up2(u0.y);
            acc[2] += up2(u0.z);
            acc[3] += up2(u0.w);
        }
    }

    float b[8] = {acc[0].x, acc[0].y, acc[1].x, acc[1].y,
                  acc[2].x, acc[2].y, acc[3].x, acc[3].y};
    const float sc = dc * dc;
    if (MODE == 1) {
#pragma unroll
        for (int j = 0; j < 8; j++) {
            float h = b[j];
            h = (h >= 0.f) ? h : 0.01f * h;
            b[j] = sc * h;
        }
    } else {
#pragma unroll
        for (int j = 0; j < 8; j++) b[j] *= sc;
    }
    uint4 o;
    o.x = (uint32)f2bf(b[0]) | ((uint32)f2bf(b[1]) << 16);
    o.y = (uint32)f2bf(b[2]) | ((uint32)f2bf(b[3]) << 16);
    o.z = (uint32)f2bf(b[4]) | ((uint32)f2bf(b[5]) << 16);
    o.w = (uint32)f2bf(b[6]) | ((uint32)f2bf(b[7]) << 16);
    *(uint4*)(Hh + (size_t)node * FEAT + l16 * 8) = o;
}

// ---------------- gather pass 3 + FUSED global_add_pool (wave-serial) --------
// R3-proven structure (4 groups split the edge list, 16-shfl reduce, register
// pool accumulator, CONTIGUOUS wave-wide 2-instruction atomic flush — R10's
// strided per-lane flush caused 8x write amplification, reverted).  R11 change:
// 8 nodes per wave (was 16) -> 12500 waves / 3125 blocks, 2x parallelism for
// more in-flight edge-list walks; flush count ~13K, still contiguous.
__global__ __launch_bounds__(256) void gatherpool_kernel(const int* __restrict__ off,
                                                         const int* __restrict__ srcArr,
                                                         const float* __restrict__ dinv,
                                                         const uint4* __restrict__ table,
                                                         const int* __restrict__ batch,
                                                         float* __restrict__ P, int n) {
    const int t = threadIdx.x;
    const int wave = blockIdx.x * 4 + (t >> 6);
    const int lane = t & 63;
    const int grp = lane >> 4;
    const int l16 = lane & 15;

    const int node0 = wave * 8;
    if (node0 >= n) return;
    const int node1 = min(node0 + 8, n);

    float pacc[8];
#pragma unroll
    for (int j = 0; j < 8; j++) pacc[j] = 0.f;
    int cur = batch[node0];

    for (int node = node0; node < node1; node++) {
        float dc = dinv[node];
        f32x2 acc[4];
        if (grp == 0) {  // self-loop term (prescaled input: raw add)
            uint4 v = table[(size_t)node * 16 + l16];
            acc[0] = up2(v.x);
            acc[1] = up2(v.y);
            acc[2] = up2(v.z);
            acc[3] = up2(v.w);
        } else {
#pragma unroll
            for (int j = 0; j < 4; j++) acc[j] = (f32x2){0.f, 0.f};
        }

        int s = off[node], e = off[node + 1];
        int i = s + grp;
        for (; i + 4 < e; i += 8) {
            int r0 = srcArr[i];
            int r1 = srcArr[i + 4];
            uint4 u0 = table[(size_t)r0 * 16 + l16];
            uint4 u1 = table[(size_t)r1 * 16 + l16];
            acc[0] += up2(u0.x) + up2(u1.x);
            acc[1] += up2(u0.y) + up2(u1.y);
            acc[2] += up2(u0.z) + up2(u1.z);
            acc[3] += up2(u0.w) + up2(u1.w);
        }
        if (i < e) {
            int r0 = srcArr[i];
            uint4 u0 = table[(size_t)r0 * 16 + l16];
            acc[0] += up2(u0.x);
            acc[1] += up2(u0.y);
            acc[2] += up2(u0.z);
            acc[3] += up2(u0.w);
        }

        float b[8] = {acc[0].x, acc[0].y, acc[1].x, acc[1].y,
                      acc[2].x, acc[2].y, acc[3].x, acc[3].y};
#pragma unroll
        for (int j = 0; j < 8; j++) {
            b[j] += __shfl_xor(b[j], 16);
            b[j] += __shfl_xor(b[j], 32);
        }

        int g = batch[node];  // uniform across the wave
        if (g != cur) {       // uniform branch (sorted batch)
            atomicAdd(&P[(size_t)cur * FEAT + l16 * 8 + 2 * grp], pacc[2 * grp]);
            atomicAdd(&P[(size_t)cur * FEAT + l16 * 8 + 2 * grp + 1], pacc[2 * grp + 1]);
#pragma unroll
            for (int j = 0; j < 8; j++) pacc[j] = 0.f;
            cur = g;
        }
#pragma unroll
        for (int j = 0; j < 8; j++) pacc[j] += dc * b[j];
    }
    // final flush (contiguous: 64 lanes x 4B per instruction)
    atomicAdd(&P[(size_t)cur * FEAT + l16 * 8 + 2 * grp], pacc[2 * grp]);
    atomicAdd(&P[(size_t)cur * FEAT + l16 * 8 + 2 * grp + 1], pacc[2 * grp + 1]);
}

// ---------------- final tiny GEMM: out[g] = P[g] @ W2 (fp32) -----------------
__global__ __launch_bounds__(128) void pgemm_kernel(const float* __restrict__ P,
                                                    const float* __restrict__ W2,
                                                    float* __restrict__ out) {
    __shared__ float sP[FEAT];
    const int g = blockIdx.x;
    const int t = threadIdx.x;
    sP[t] = P[(size_t)g * FEAT + t];
    __syncthreads();
    float o = 0.f;
#pragma unroll 4
    for (int k = 0; k < FEAT; k++) o += sP[k] * W2[(size_t)k * FEAT + t];
    out[(size_t)g * FEAT + t] = o;
}

extern "C" void kernel_launch(void* const* d_in, const int* in_sizes, int n_in,
                              void* d_out, int out_size, void* d_ws, size_t ws_size,
                              hipStream_t stream) {
    const float* x = (const float*)d_in[0];
    const int* ei = (const int*)d_in[1];
    const int* batch = (const int*)d_in[2];
    const float* W0 = (const float*)d_in[3];
    const float* W1 = (const float*)d_in[4];
    const float* W2 = (const float*)d_in[5];
    float* out = (float*)d_out;

    const int N = in_sizes[0] / FEAT;  // 100000
    const int E = in_sizes[1] / 2;     // 640000
    const int G = out_size / FEAT;     // 512

    const int* rowI = ei;
    const int* colI = ei + E;

    char* ws = (char*)d_ws;
    auto take = [&](size_t bytes) {
        char* p = ws;
        ws += (bytes + 15) & ~(size_t)15;
        return p;
    };
    int* counts    = (int*)take((size_t)N * 4);
    int* off       = (int*)take((size_t)(N + 1) * 4);
    int* nxt       = (int*)take((size_t)N * 4);
    float* dinv    = (float*)take((size_t)N * 4);
    int* flagval   = (int*)take(128 * 4);
    int* srcArr    = (int*)take((size_t)E * 4);
    ushort16* W01t = (ushort16*)take((size_t)16384 * 2);
    float* Pbuf    = (float*)take((size_t)G * FEAT * 4);
    ushort16* bufA = (ushort16*)take((size_t)N * FEAT * 2);
    ushort16* bufB = (ushort16*)take((size_t)N * FEAT * 2);

    const int nb = (N + 1023) / 1024;  // 98

    // ---- pre: zero counts + W01 + zero P + zero flags (one dispatch) ----
    pre_kernel<<<197, 256, 0, stream>>>(counts, N, W0, W1, W01t, Pbuf, flagval);

    // ---- hist (latency) || gemm-half-A (tiles [0,3125)) ----
    histgemmA_kernel<<<128 * 9, 256, 0, stream>>>(colI, counts, E, x, W01t, bufA, N);

    // ---- CSR scan (merged, parallel lookback, one dispatch) ----
    scan_chain<<<nb, 256, 0, stream>>>(counts, flagval, off, nxt, dinv, N);

    // ---- fill (latency) || gemm-half-B (tiles [3125,6250)) ----
    fillgemmB_kernel<<<512 * 7, 256, 0, stream>>>(x, W01t, bufA, N,
                                                  rowI, colI, nxt, srcArr, E);

    const int gatBlocks = (N + 15) / 16;  // 6250: 16 nodes/block, 1 node/group
    // ---- pass 1: bufB = dinv * (A Y)   (raw input, prescaled output) ----
    gather_kernel<0><<<gatBlocks, 256, 0, stream>>>(off, srcArr, dinv,
                                                    (const uint4*)bufA, bufB, N);
    // ---- pass 2: bufA = dinv * leaky(A H1)   (prescaled in & out) ----
    gather_kernel<1><<<gatBlocks, 256, 0, stream>>>(off, srcArr, dinv,
                                                    (const uint4*)bufB, bufA, N);
    // ---- pass 3: P += pool(A H3)  (wave-serial, 8 nodes/wave, reg pool) ----
    const int nWaves = (N + 7) / 8;                 // 12500 waves, 8 nodes each
    const int poolBlocks = (nWaves + 3) / 4;        // 3125 blocks x 4 waves
    gatherpool_kernel<<<poolBlocks, 256, 0, stream>>>(off, srcArr, dinv,
                                                      (const uint4*)bufA, batch,
                                                      Pbuf, N);
    // ---- out = P @ W2 ----
    pgemm_kernel<<<G, 128, 0, stream>>>(Pbuf, W2, out);
}

// Round 12
// 306.633 us; speedup vs baseline: 1.2342x; 1.0334x over previous
//
#include <hip/hip_runtime.h>
#include <hip/hip_bf16.h>

#define FEAT 128

typedef unsigned int uint32;
typedef unsigned short ushort16;
typedef __attribute__((ext_vector_type(8))) short short8;
typedef __attribute__((ext_vector_type(4))) float v4f;
typedef __attribute__((ext_vector_type(2))) float f32x2;

// ---- bf16 helpers (RNE round; bf16->f32 is exact shift) ---------------------
__device__ __forceinline__ ushort16 f2bf(float f) {
    uint32 u = __float_as_uint(f);
    u += 0x7fffu + ((u >> 16) & 1u);
    return (ushort16)(u >> 16);
}
__device__ __forceinline__ float bflo(uint32 u) { return __uint_as_float(u << 16); }
__device__ __forceinline__ float bfhi(uint32 u) { return __uint_as_float(u & 0xffff0000u); }
__device__ __forceinline__ f32x2 up2(uint32 u) { return (f32x2){bflo(u), bfhi(u)}; }

// ---------------- shared gemm body: half-W-per-wave register-resident --------
__device__ __forceinline__ void gemm_body(const float* __restrict__ A,
                                          const ushort16* __restrict__ Wt,
                                          ushort16* __restrict__ Ch, int n,
                                          int pairId, int pairStride,
                                          int tile0, int tile1, int t) {
    const int w = t >> 6;
    const int lane = t & 63;
    const int quad = lane >> 4;
    const int l16 = lane & 15;
    const int colBase = (w & 1) * 64;

    short8 wf[4][4];
#pragma unroll
    for (int ct = 0; ct < 4; ct++) {
        const ushort16* wp = Wt + (size_t)(colBase + ct * 16 + l16) * FEAT + quad * 8;
#pragma unroll
        for (int ks = 0; ks < 4; ks++) wf[ct][ks] = *(const short8*)(wp + ks * 32);
    }

    int tile = tile0 + pairId;
    if (tile >= tile1) return;

    auto loadA = [&](int tl, short8 (&a)[4]) {
        const int rowi = tl * 16 + l16;
        if (rowi < n) {
#pragma unroll
            for (int ks = 0; ks < 4; ks++) {
                const float* ap = A + (size_t)rowi * FEAT + quad * 8 + ks * 32;
                float4 f0 = *(const float4*)ap;
                float4 f1 = *(const float4*)(ap + 4);
                short8 v;
                v[0] = f2bf(f0.x); v[1] = f2bf(f0.y); v[2] = f2bf(f0.z); v[3] = f2bf(f0.w);
                v[4] = f2bf(f1.x); v[5] = f2bf(f1.y); v[6] = f2bf(f1.z); v[7] = f2bf(f1.w);
                a[ks] = v;
            }
        } else {
#pragma unroll
            for (int ks = 0; ks < 4; ks++) a[ks] = (short8)0;
        }
    };

    short8 aCur[4];
    loadA(tile, aCur);

    while (tile < tile1) {
        const int nextTile = tile + pairStride;
        short8 aNxt[4];
        if (nextTile < tile1) loadA(nextTile, aNxt);

        v4f acc[4];
#pragma unroll
        for (int ct = 0; ct < 4; ct++) acc[ct] = (v4f)0.f;
#pragma unroll
        for (int ct = 0; ct < 4; ct++)
#pragma unroll
            for (int ks = 0; ks < 4; ks++)
                acc[ct] = __builtin_amdgcn_mfma_f32_16x16x32_bf16(wf[ct][ks], aCur[ks], acc[ct], 0, 0, 0);

        const int rowi = tile * 16 + l16;
        if (rowi < n) {
#pragma unroll
            for (int ct = 0; ct < 4; ct++) {
                uint2 o;
                o.x = (uint32)f2bf(acc[ct][0]) | ((uint32)f2bf(acc[ct][1]) << 16);
                o.y = (uint32)f2bf(acc[ct][2]) | ((uint32)f2bf(acc[ct][3]) << 16);
                *(uint2*)(Ch + (size_t)rowi * FEAT + colBase + ct * 16 + quad * 4) = o;
            }
        }

        tile = nextTile;
#pragma unroll
        for (int ks = 0; ks < 4; ks++) aCur[ks] = aNxt[ks];
    }
}

// ---------------- pre: zero counts + W01=W0@W1 + zero(P) + zero(flagval) -----
__global__ __launch_bounds__(256) void pre_kernel(int* __restrict__ counts, int n,
                                                  const float* __restrict__ W0,
                                                  const float* __restrict__ W1,
                                                  ushort16* __restrict__ W01t,
                                                  float* __restrict__ Pbuf,
                                                  int* __restrict__ flagval) {
    int b = blockIdx.x;
    int t = threadIdx.x;
    if (b < 100) {
        int idx = (b * 256 + t) * 4;
        if (idx + 3 < n) {
            *(int4*)(counts + idx) = make_int4(0, 0, 0, 0);
        } else {
            for (int i = idx; i < n; i++) counts[i] = 0;
        }
    } else if (b < 164) {
        __shared__ float sW0[2][FEAT];
        int wb = b - 100;  // [0, 64)
        int lk = t >> 7;
        int ncol = t & 127;
        int k = wb * 2 + lk;
        sW0[lk][ncol] = W0[(size_t)k * FEAT + ncol];
        __syncthreads();
        float acc = 0.f;
#pragma unroll 4
        for (int j = 0; j < FEAT; j++)
            acc += sW0[lk][j] * W1[(size_t)j * FEAT + ncol];
        W01t[(size_t)ncol * FEAT + k] = f2bf(acc);  // [n][k], transposed for MFMA
    } else if (b < 196) {
        int zb = b - 164;  // [0, 32): 512*128 floats
        float4 z = make_float4(0.f, 0.f, 0.f, 0.f);
        float* p = Pbuf + (size_t)zb * 2048 + t * 8;
        *(float4*)p = z;
        *(float4*)(p + 4) = z;
    } else {
        if (t < 128) flagval[t] = 0;  // scan lookback flags
    }
}

// ---------------- FUSED hist + gemm-half-A -----------------------------------
__global__ __launch_bounds__(256) void histgemmA_kernel(const int* __restrict__ col,
                                                        int* __restrict__ counts, int E,
                                                        const float* __restrict__ A,
                                                        const ushort16* __restrict__ Wt,
                                                        ushort16* __restrict__ Ch, int n) {
    const int b = blockIdx.x;
    const int r9 = b % 9;
    const int g9 = b / 9;
    const int t = threadIdx.x;
    if (r9 >= 4) {
        // hist role: 5/9 -> hist block id in [0, 640)
        int hb = g9 * 5 + (r9 - 4);
        int id = hb * 256 + t;
        if (id * 4 + 3 < E) {
            int4 c4 = *(const int4*)(col + id * 4);
            atomicAdd(&counts[c4.x], 1);
            atomicAdd(&counts[c4.y], 1);
            atomicAdd(&counts[c4.z], 1);
            atomicAdd(&counts[c4.w], 1);
        } else {
            for (int e = id * 4; e < E; e++) atomicAdd(&counts[col[e]], 1);
        }
        return;
    }
    // gemm role: 4/9 -> gemm block id in [0, 512); 1024 wave-pairs, stride 1024
    int gb = g9 * 4 + r9;
    gemm_body(A, Wt, Ch, n, gb * 2 + ((t >> 6) >> 1), 1024, 0, 3125, t);
}

// ---------------- merged CSR scan (publish + PARALLEL lookback, R7-proven) ---
__global__ __launch_bounds__(256) void scan_chain(const int* __restrict__ counts,
                                                  int* __restrict__ flagval,
                                                  int* __restrict__ off, int* __restrict__ nxt,
                                                  float* __restrict__ dinv, int n) {
    __shared__ int s[256];
    __shared__ int sb[256];
    const int b = blockIdx.x;
    const int base = b * 1024;
    const int t = threadIdx.x;
    int c[4];
    int sum = 0;
#pragma unroll
    for (int i = 0; i < 4; i++) {
        int idx = base + t * 4 + i;
        c[i] = (idx < n) ? counts[idx] : 0;
        sum += c[i];
    }
    int v0 = sum;
    s[t] = sum;
    __syncthreads();
    for (int o = 1; o < 256; o <<= 1) {
        int v = (t >= o) ? s[t - o] : 0;
        __syncthreads();
        s[t] += v;
        __syncthreads();
    }
    if (t == 255) atomicExch(&flagval[b], s[255] + 1);  // publish (no wait)
    // parallel lookback: thread t polls predecessor t's flag
    int lv = 0;
    if (t < b) {
        for (;;) {
            lv = atomicAdd(&flagval[t], 0);
            if (lv != 0) break;
            __builtin_amdgcn_s_sleep(2);
        }
        lv -= 1;
    }
    sb[t] = lv;
    __syncthreads();
    for (int o = 128; o > 0; o >>= 1) {
        if (t < o) sb[t] += sb[t + o];
        __syncthreads();
    }
    const int sBase = sb[0];
    int excl = s[t] - v0 + sBase;
#pragma unroll
    for (int i = 0; i < 4; i++) {
        int idx = base + t * 4 + i;
        if (idx < n) {
            off[idx] = excl;
            nxt[idx] = excl;
            dinv[idx] = rsqrtf((float)(c[i] + 1));  // +1 = self loop
        }
        excl += c[i];
    }
    if (b == gridDim.x - 1 && t == 255) off[n] = excl;  // == E
}

// ---------------- FUSED fill + gemm-half-B -----------------------------------
__global__ __launch_bounds__(256) void fillgemmB_kernel(const float* __restrict__ A,
                                                        const ushort16* __restrict__ Wt,
                                                        ushort16* __restrict__ Ch, int n,
                                                        const int* __restrict__ row,
                                                        const int* __restrict__ col,
                                                        int* __restrict__ nxt,
                                                        int* __restrict__ srcArr, int E) {
    const int b = blockIdx.x;
    const int r7 = b % 7;
    const int g7 = b / 7;
    const int t = threadIdx.x;
    if (r7 >= 2) {
        // fill role: 5/7 -> fill block id in [0, 2560)
        int fb = g7 * 5 + (r7 - 2);
        int e = fb * 256 + t;
        if (e < E) {
            int c = col[e], r = row[e];
            int p = atomicAdd(&nxt[c], 1);
            __builtin_nontemporal_store(r, &srcArr[p]);
        }
        return;
    }
    // gemm role: 2/7 -> gemm block id in [0, 1024); 2048 wave-pairs, stride 2048
    int gb = g7 * 2 + r7;
    gemm_body(A, Wt, Ch, n, gb * 2 + ((t >> 6) >> 1), 2048, 3125, 6250, t);
}

// ---------------- gather-propagate, ONE NODE PER 16-LANE GROUP (R9-proven) ---
// Each group owns ONE node, walks ALL its edges unroll-4: 16 independent
// row-loads in flight per wave, no shfl, all lanes store.  R9: 48 -> ~39us.
//   MODE 0: raw input.  writes dc^2 * (dc*T[c] + sum dinv[src]*T[src]).
//   MODE 1: prescaled.  writes dc^2 * leaky(T[c] + sum T[src]).
template <int MODE>
__global__ __launch_bounds__(256) void gather_kernel(const int* __restrict__ off,
                                                     const int* __restrict__ srcArr,
                                                     const float* __restrict__ dinv,
                                                     const uint4* __restrict__ table,
                                                     ushort16* __restrict__ Hh, int n) {
    const int t = threadIdx.x;
    const int lane = t & 63;
    const int grp = lane >> 4;
    const int l16 = lane & 15;
    const int node = blockIdx.x * 16 + (t >> 6) * 4 + grp;  // one node per group
    if (node >= n) return;

    const float dc = dinv[node];

    // self-loop term
    uint4 v = table[(size_t)node * 16 + l16];
    f32x2 acc[4];
    if (MODE == 0) {
        f32x2 w0 = (f32x2){dc, dc};
        acc[0] = w0 * up2(v.x);
        acc[1] = w0 * up2(v.y);
        acc[2] = w0 * up2(v.z);
        acc[3] = w0 * up2(v.w);
    } else {
        acc[0] = up2(v.x);
        acc[1] = up2(v.y);
        acc[2] = up2(v.z);
        acc[3] = up2(v.w);
    }

    const int s = off[node], e = off[node + 1];
    int i = s;
    for (; i + 3 < e; i += 4) {
        int r0 = srcArr[i];
        int r1 = srcArr[i + 1];
        int r2 = srcArr[i + 2];
        int r3 = srcArr[i + 3];
        uint4 u0 = table[(size_t)r0 * 16 + l16];
        uint4 u1 = table[(size_t)r1 * 16 + l16];
        uint4 u2 = table[(size_t)r2 * 16 + l16];
        uint4 u3 = table[(size_t)r3 * 16 + l16];
        if (MODE == 0) {
            f32x2 n0 = (f32x2){dinv[r0], dinv[r0]};
            f32x2 n1 = (f32x2){dinv[r1], dinv[r1]};
            f32x2 n2 = (f32x2){dinv[r2], dinv[r2]};
            f32x2 n3 = (f32x2){dinv[r3], dinv[r3]};
            acc[0] += n0 * up2(u0.x) + n1 * up2(u1.x);
            acc[1] += n0 * up2(u0.y) + n1 * up2(u1.y);
            acc[2] += n0 * up2(u0.z) + n1 * up2(u1.z);
            acc[3] += n0 * up2(u0.w) + n1 * up2(u1.w);
            acc[0] += n2 * up2(u2.x) + n3 * up2(u3.x);
            acc[1] += n2 * up2(u2.y) + n3 * up2(u3.y);
            acc[2] += n2 * up2(u2.z) + n3 * up2(u3.z);
            acc[3] += n2 * up2(u2.w) + n3 * up2(u3.w);
        } else {
            acc[0] += up2(u0.x) + up2(u1.x) + up2(u2.x) + up2(u3.x);
            acc[1] += up2(u0.y) + up2(u1.y) + up2(u2.y) + up2(u3.y);
            acc[2] += up2(u0.z) + up2(u1.z) + up2(u2.z) + up2(u3.z);
            acc[3] += up2(u0.w) + up2(u1.w) + up2(u2.w) + up2(u3.w);
        }
    }
    for (; i < e; i++) {
        int r0 = srcArr[i];
        uint4 u0 = table[(size_t)r0 * 16 + l16];
        if (MODE == 0) {
            f32x2 n0 = (f32x2){dinv[r0], dinv[r0]};
            acc[0] += n0 * up2(u0.x);
            acc[1] += n0 * up2(u0.y);
            acc[2] += n0 * up2(u0.z);
            acc[3] += n0 * up2(u0.w);
        } else {
            acc[0] += up2(u0.x);
            acc[1] += up2(u0.y);
            acc[2] += up2(u0.z);
            acc[3] += up2(u0.w);
        }
    }

    float b[8] = {acc[0].x, acc[0].y, acc[1].x, acc[1].y,
                  acc[2].x, acc[2].y, acc[3].x, acc[3].y};
    const float sc = dc * dc;
    if (MODE == 1) {
#pragma unroll
        for (int j = 0; j < 8; j++) {
            float h = b[j];
            h = (h >= 0.f) ? h : 0.01f * h;
            b[j] = sc * h;
        }
    } else {
#pragma unroll
        for (int j = 0; j < 8; j++) b[j] *= sc;
    }
    uint4 o;
    o.x = (uint32)f2bf(b[0]) | ((uint32)f2bf(b[1]) << 16);
    o.y = (uint32)f2bf(b[2]) | ((uint32)f2bf(b[3]) << 16);
    o.z = (uint32)f2bf(b[4]) | ((uint32)f2bf(b[5]) << 16);
    o.w = (uint32)f2bf(b[6]) | ((uint32)f2bf(b[7]) << 16);
    *(uint4*)(Hh + (size_t)node * FEAT + l16 * 8) = o;
}

// ---------------- gather pass 3 + FUSED pool, 2 NODES IN FLIGHT (R12) --------
// 16 nodes/wave as 8 PAIRS (same 6250 waves -> same flush count/traffic as the
// proven R3 form; R11 showed flush traffic ~ wave count).  Groups 0-1 walk
// node A's edges (2-way split), groups 2-3 walk node B's — single loop with
// per-lane bounds so A and B row-loads issue in the SAME iterations (2x MLP).
// Reduce: one shfl_xor(16) per pair (vs xor16+xor32 per node = half the shfl
// count), then one shfl_xor(32) exchange gives every lane both A and B totals
// -> pacc uniform across 64 lanes -> R3's contiguous 2-instruction flush
// unchanged.  gA!=gB boundary = uniform branch, ~511 occurrences total.
__global__ __launch_bounds__(256) void gatherpool_kernel(const int* __restrict__ off,
                                                         const int* __restrict__ srcArr,
                                                         const float* __restrict__ dinv,
                                                         const uint4* __restrict__ table,
                                                         const int* __restrict__ batch,
                                                         float* __restrict__ P, int n) {
    const int t = threadIdx.x;
    const int wave = blockIdx.x * 4 + (t >> 6);
    const int lane = t & 63;
    const int grp = lane >> 4;
    const int l16 = lane & 15;
    const int role = grp >> 1;  // 0 -> node A, 1 -> node B
    const int sub = grp & 1;    // 2-way edge split within the role

    const int node0 = wave * 16;
    if (node0 >= n) return;

    float pacc[8];
#pragma unroll
    for (int j = 0; j < 8; j++) pacc[j] = 0.f;
    int cur = batch[node0];

    auto flush = [&]() {
        atomicAdd(&P[(size_t)cur * FEAT + l16 * 8 + 2 * grp], pacc[2 * grp]);
        atomicAdd(&P[(size_t)cur * FEAT + l16 * 8 + 2 * grp + 1], pacc[2 * grp + 1]);
#pragma unroll
        for (int j = 0; j < 8; j++) pacc[j] = 0.f;
    };

    for (int p = 0; p < 8; p++) {
        const int nA = node0 + 2 * p;
        if (nA >= n) break;
        const int nB = nA + 1;                   // n even -> nB < n always here
        const int myNode = nA + role;
        const bool mValid = myNode < n;

        const float dcm = mValid ? dinv[myNode] : 0.f;
        f32x2 acc[4];
        if (mValid && sub == 0) {  // self-loop term (prescaled input: raw add)
            uint4 v = table[(size_t)myNode * 16 + l16];
            acc[0] = up2(v.x);
            acc[1] = up2(v.y);
            acc[2] = up2(v.z);
            acc[3] = up2(v.w);
        } else {
#pragma unroll
            for (int j = 0; j < 4; j++) acc[j] = (f32x2){0.f, 0.f};
        }

        int s = 0, e = 0;
        if (mValid) { s = off[myNode]; e = off[myNode + 1]; }
        int i = s + sub;
        for (; i + 2 < e; i += 4) {  // unroll-2, stride-2 within the role
            int r0 = srcArr[i];
            int r1 = srcArr[i + 2];
            uint4 u0 = table[(size_t)r0 * 16 + l16];
            uint4 u1 = table[(size_t)r1 * 16 + l16];
            acc[0] += up2(u0.x) + up2(u1.x);
            acc[1] += up2(u0.y) + up2(u1.y);
            acc[2] += up2(u0.z) + up2(u1.z);
            acc[3] += up2(u0.w) + up2(u1.w);
        }
        if (i < e) {
            int r0 = srcArr[i];
            uint4 u0 = table[(size_t)r0 * 16 + l16];
            acc[0] += up2(u0.x);
            acc[1] += up2(u0.y);
            acc[2] += up2(u0.z);
            acc[3] += up2(u0.w);
        }

        float b[8] = {acc[0].x, acc[0].y, acc[1].x, acc[1].y,
                      acc[2].x, acc[2].y, acc[3].x, acc[3].y};
        // reduce within role pair (0<->1, 2<->3) and apply dinv scale
#pragma unroll
        for (int j = 0; j < 8; j++) {
            b[j] += __shfl_xor(b[j], 16);
            b[j] *= dcm;
        }
        // cross-role exchange: every lane gets both A and B totals
        float av[8], bv[8];
#pragma unroll
        for (int j = 0; j < 8; j++) {
            float o = __shfl_xor(b[j], 32);
            av[j] = (role == 0) ? b[j] : o;
            bv[j] = (role == 0) ? o : b[j];
        }

        const int gA = batch[nA];
        const int gB = (nB < n) ? batch[nB] : gA;
        if (gA != cur) { flush(); cur = gA; }   // uniform (sorted batch)
#pragma unroll
        for (int j = 0; j < 8; j++) pacc[j] += av[j];
        if (gB != cur) { flush(); cur = gB; }   // uniform, rare
        if (nB < n) {
#pragma unroll
            for (int j = 0; j < 8; j++) pacc[j] += bv[j];
        }
    }
    flush();  // final (contiguous: 64 lanes x 4B per instruction)
}

// ---------------- final tiny GEMM: out[g] = P[g] @ W2 (fp32) -----------------
__global__ __launch_bounds__(128) void pgemm_kernel(const float* __restrict__ P,
                                                    const float* __restrict__ W2,
                                                    float* __restrict__ out) {
    __shared__ float sP[FEAT];
    const int g = blockIdx.x;
    const int t = threadIdx.x;
    sP[t] = P[(size_t)g * FEAT + t];
    __syncthreads();
    float o = 0.f;
#pragma unroll 4
    for (int k = 0; k < FEAT; k++) o += sP[k] * W2[(size_t)k * FEAT + t];
    out[(size_t)g * FEAT + t] = o;
}

extern "C" void kernel_launch(void* const* d_in, const int* in_sizes, int n_in,
                              void* d_out, int out_size, void* d_ws, size_t ws_size,
                              hipStream_t stream) {
    const float* x = (const float*)d_in[0];
    const int* ei = (const int*)d_in[1];
    const int* batch = (const int*)d_in[2];
    const float* W0 = (const float*)d_in[3];
    const float* W1 = (const float*)d_in[4];
    const float* W2 = (const float*)d_in[5];
    float* out = (float*)d_out;

    const int N = in_sizes[0] / FEAT;  // 100000
    const int E = in_sizes[1] / 2;     // 640000
    const int G = out_size / FEAT;     // 512

    const int* rowI = ei;
    const int* colI = ei + E;

    char* ws = (char*)d_ws;
    auto take = [&](size_t bytes) {
        char* p = ws;
        ws += (bytes + 15) & ~(size_t)15;
        return p;
    };
    int* counts    = (int*)take((size_t)N * 4);
    int* off       = (int*)take((size_t)(N + 1) * 4);
    int* nxt       = (int*)take((size_t)N * 4);
    float* dinv    = (float*)take((size_t)N * 4);
    int* flagval   = (int*)take(128 * 4);
    int* srcArr    = (int*)take((size_t)E * 4);
    ushort16* W01t = (ushort16*)take((size_t)16384 * 2);
    float* Pbuf    = (float*)take((size_t)G * FEAT * 4);
    ushort16* bufA = (ushort16*)take((size_t)N * FEAT * 2);
    ushort16* bufB = (ushort16*)take((size_t)N * FEAT * 2);

    const int nb = (N + 1023) / 1024;  // 98

    // ---- pre: zero counts + W01 + zero P + zero flags (one dispatch) ----
    pre_kernel<<<197, 256, 0, stream>>>(counts, N, W0, W1, W01t, Pbuf, flagval);

    // ---- hist (latency) || gemm-half-A (tiles [0,3125)) ----
    histgemmA_kernel<<<128 * 9, 256, 0, stream>>>(colI, counts, E, x, W01t, bufA, N);

    // ---- CSR scan (merged, parallel lookback, one dispatch) ----
    scan_chain<<<nb, 256, 0, stream>>>(counts, flagval, off, nxt, dinv, N);

    // ---- fill (latency) || gemm-half-B (tiles [3125,6250)) ----
    fillgemmB_kernel<<<512 * 7, 256, 0, stream>>>(x, W01t, bufA, N,
                                                  rowI, colI, nxt, srcArr, E);

    const int gatBlocks = (N + 15) / 16;  // 6250: 16 nodes/block, 1 node/group
    // ---- pass 1: bufB = dinv * (A Y)   (raw input, prescaled output) ----
    gather_kernel<0><<<gatBlocks, 256, 0, stream>>>(off, srcArr, dinv,
                                                    (const uint4*)bufA, bufB, N);
    // ---- pass 2: bufA = dinv * leaky(A H1)   (prescaled in & out) ----
    gather_kernel<1><<<gatBlocks, 256, 0, stream>>>(off, srcArr, dinv,
                                                    (const uint4*)bufB, bufA, N);
    // ---- pass 3: P += pool(A H3)  (16 nodes/wave as 8 pairs, reg pool) ----
    const int nWaves = (N + 15) / 16;               // 6250 waves, 16 nodes each
    const int poolBlocks = (nWaves + 3) / 4;        // 1563 blocks x 4 waves
    gatherpool_kernel<<<poolBlocks, 256, 0, stream>>>(off, srcArr, dinv,
                                                      (const uint4*)bufA, batch,
                                                      Pbuf, N);
    // ---- out = P @ W2 ----
    pgemm_kernel<<<G, 128, 0, stream>>>(Pbuf, W2, out);
}